// Round 2
// baseline (88.049 us; speedup 1.0000x reference)
//
#include <hip/hip_runtime.h>
#include <hip/hip_bf16.h>

// Collapsed GAT (all fp32, per reference): x broadcast over nodes => softmax of a
// constant row is exactly uniform => attention drops out:
//   wh[b,k,h]  = sum_f x[b,-1,f] * W_heads[k,f,h]
//   hp[b,k,h]  = elu(wh[b,k,h])
//   who[b,c]   = sum_{k,h} hp[b,k,h] * W_out[k*64+h, c]
//   out[b,c]   = bf[c] + sum_c2 who[b,c2] * WfSum[c,c2],  WfSum[c,c2]=sum_n Wf[c,n*64+c2]

// K1: reduce Wf (64 x 32768 fp32) over n into 4 partial chunks, stored
// TRANSPOSED: wsum[chunk*4096 + c2*64 + c] = sum_{n in chunk} Wf[c, n*64+c2]
__global__ __launch_bounds__(256) void k_wfsum(const float* __restrict__ Wf,
                                               float* __restrict__ wsum) {
    const int bx    = blockIdx.x;   // 0..255
    const int c     = bx >> 2;      // 0..63  (row of Wf)
    const int chunk = bx & 3;       // 0..3   (n chunk of 128)
    const int t = threadIdx.x;
    const int p = t & 15;           // c2 quad (4 floats per 16B load)
    const int g = t >> 4;           // 0..15 n-group
    const float* row = Wf + (size_t)c * 32768;

    float acc[4] = {0.f, 0.f, 0.f, 0.f};
#pragma unroll
    for (int i = 0; i < 8; ++i) {
        const int n = chunk * 128 + g + 16 * i;
        const float4 v = *reinterpret_cast<const float4*>(row + n * 64 + p * 4);
        acc[0] += v.x; acc[1] += v.y; acc[2] += v.z; acc[3] += v.w;
    }
    __shared__ float s[16][64];
#pragma unroll
    for (int e = 0; e < 4; ++e) s[g][p * 4 + e] = acc[e];
    __syncthreads();
    if (t < 64) {               // t = c2
        float sum = 0.f;
#pragma unroll
        for (int g2 = 0; g2 < 16; ++g2) sum += s[g2][t];
        wsum[chunk * 4096 + t * 64 + c] = sum;
    }
}

// K2: one block per batch element b; whole collapsed network in LDS.
__global__ __launch_bounds__(256) void k_main(const float* __restrict__ x,
                                              const float* __restrict__ W_heads,
                                              const float* __restrict__ W_out,
                                              const float* __restrict__ bias,
                                              const float* __restrict__ wsum,
                                              float* __restrict__ out) {
    const int b = blockIdx.x;   // 0..31
    const int t = threadIdx.x;  // 0..255

    __shared__ float xl[128];
    __shared__ float hp[512];
    __shared__ float who[64];
    __shared__ float red[256];

    // stage 1: last time-step features (S=12, F=128)
    if (t < 128) xl[t] = x[b * 1536 + 11 * 128 + t];
    __syncthreads();

    // stage 2: wh + elu. 512 outputs; each thread does 2 adjacent h via float2 loads.
    {
        const int k = t >> 5;          // 0..7
        const int h = (t & 31) * 2;    // 0,2,...,62
        const float* wb = W_heads + k * 8192 + h;
        float a0 = 0.f, a1 = 0.f;
#pragma unroll 8
        for (int f = 0; f < 128; ++f) {
            const float2 v = *reinterpret_cast<const float2*>(wb + f * 64);
            const float xv = xl[f];
            a0 += xv * v.x;
            a1 += xv * v.y;
        }
        hp[k * 64 + h]     = (a0 > 0.f) ? a0 : expm1f(a0);
        hp[k * 64 + h + 1] = (a1 > 0.f) ? a1 : expm1f(a1);
    }
    __syncthreads();

    // stage 3: who[c] = sum_{j<512} hp[j] * W_out[j*64 + c]
    {
        const int c  = t & 63;
        const int jg = t >> 6;   // 0..3
        float acc = 0.f;
#pragma unroll 8
        for (int j = jg * 128; j < jg * 128 + 128; ++j)
            acc += hp[j] * W_out[j * 64 + c];
        red[t] = acc;
    }
    __syncthreads();
    if (t < 64) who[t] = red[t] + red[t + 64] + red[t + 128] + red[t + 192];
    __syncthreads();

    // stage 4: out[b,c] = bf[c] + sum_c2 who[c2] * WfSum[c,c2] (partials, transposed)
    {
        const int c  = t & 63;
        const int cg = t >> 6;   // 0..3
        float acc = 0.f;
#pragma unroll
        for (int c2 = cg * 16; c2 < cg * 16 + 16; ++c2) {
            const int o = c2 * 64 + c;
            const float w = wsum[o] + wsum[4096 + o] + wsum[8192 + o] + wsum[12288 + o];
            acc += who[c2] * w;
        }
        red[t] = acc;
    }
    __syncthreads();
    if (t < 64)
        out[b * 64 + t] = red[t] + red[t + 64] + red[t + 128] + red[t + 192] + bias[t];
}

extern "C" void kernel_launch(void* const* d_in, const int* in_sizes, int n_in,
                              void* d_out, int out_size, void* d_ws, size_t ws_size,
                              hipStream_t stream) {
    const float* x       = (const float*)d_in[0]; // (32,12,128)
    const float* W_heads = (const float*)d_in[1]; // (8,128,64)
    // d_in[2], d_in[3]: a1_heads/a2_heads — unused (softmax of constant is uniform)
    const float* W_out   = (const float*)d_in[4]; // (512,64)
    // d_in[5], d_in[6]: a1_out/a2_out — unused
    const float* Wf      = (const float*)d_in[7]; // (64,32768)
    const float* bias    = (const float*)d_in[8]; // (64,)
    float* wsum = (float*)d_ws;  // 4 chunks * 64*64 fp32 = 64 KB

    k_wfsum<<<256, 256, 0, stream>>>(Wf, wsum);
    k_main<<<32, 256, 0, stream>>>(x, W_heads, W_out, bias, wsum, (float*)d_out);
}

// Round 3
// 80.584 us; speedup vs baseline: 1.0926x; 1.0926x over previous
//
#include <hip/hip_runtime.h>
#include <hip/hip_bf16.h>

// Collapsed GAT (all fp32): x is broadcast over nodes => softmax of a constant
// row is exactly uniform => both attention layers drop out:
//   wh[b,k,h]  = sum_f x[b,-1,f] * W_heads[k,f,h]
//   hp[b,k,h]  = elu(wh[b,k,h])
//   who[b,c]   = sum_{k,h} hp[b,k,h] * W_out[k*64+h, c]
//   out[b,c]   = bf[c] + sum_c2 who[b,c2] * WfSum[c,c2],  WfSum[c,c2]=sum_n Wf[c,n*64+c2]
//
// R3: latency-oriented restructure. Kernel A = 192 blocks (64 WfSum-row blocks +
// 128 hp blocks, each owning 4 h-columns for all 32 batches). Kernel B = 32
// blocks (per batch): who matvec (float4 W_out) + final 64x64 matvec + bias.
// ws layout: wsumT[ c2*64 + c ] (16 KB) | HP[ b*512 + j ] (64 KB)

__global__ __launch_bounds__(256) void kA(const float* __restrict__ Wf,
                                          const float* __restrict__ x,
                                          const float* __restrict__ W_heads,
                                          float* __restrict__ ws) {
    float* wsumT = ws;            // 64*64
    float* HP    = ws + 4096;     // 32*512
    const int t = threadIdx.x;

    if (blockIdx.x < 64) {
        // --- reduce one full row c of Wf (64 x 32768) over n: 128 KB streamed ---
        const int c = blockIdx.x;
        const float* row = Wf + (size_t)c * 32768;
        const int p = t & 15;     // c2 quad
        const int ng = t >> 4;    // 0..15 n-group
        float ax = 0.f, ay = 0.f, az = 0.f, aw = 0.f;
#pragma unroll 8
        for (int i = 0; i < 32; ++i) {
            const float4 v = *reinterpret_cast<const float4*>(row + (ng + 16 * i) * 64 + p * 4);
            ax += v.x; ay += v.y; az += v.z; aw += v.w;
        }
        __shared__ float s[16][64];
        s[ng][p * 4 + 0] = ax; s[ng][p * 4 + 1] = ay;
        s[ng][p * 4 + 2] = az; s[ng][p * 4 + 3] = aw;
        __syncthreads();
        if (t < 64) {             // t = c2
            float sum = 0.f;
#pragma unroll
            for (int g = 0; g < 16; ++g) sum += s[g][t];
            wsumT[t * 64 + c] = sum;   // transposed: [c2][c]
        }
    } else {
        // --- hp for 4 h-columns (one k), all 32 batches ---
        const int idx = blockIdx.x - 64;   // 0..127
        const int k  = idx >> 4;           // 0..7
        const int hq = (idx & 15) * 4;     // 0,4,...,60
        __shared__ float xl[32][129];      // +1 pad: breaks 16-way bank aliasing
#pragma unroll
        for (int r = 0; r < 4; ++r) {
            const int id = t + 256 * r;
            const int b = id >> 5, fq = id & 31;
            const float4 v = *reinterpret_cast<const float4*>(x + b * 1536 + 1408 + fq * 4);
            xl[b][fq * 4 + 0] = v.x; xl[b][fq * 4 + 1] = v.y;
            xl[b][fq * 4 + 2] = v.z; xl[b][fq * 4 + 3] = v.w;
        }
        __syncthreads();
        const int fh = t & 1;              // f half
        const int e  = (t >> 1) & 3;       // h within quad
        const int b  = t >> 3;             // 0..31
        const float* wp = W_heads + k * 8192 + fh * 4096 + hq + e;  // step f*64
        float acc = 0.f;
#pragma unroll 16
        for (int f = 0; f < 64; ++f)
            acc += xl[b][fh * 64 + f] * wp[f * 64];
        acc += __shfl_xor(acc, 1);         // combine the two f-halves
        if (fh == 0) {
            const float v = (acc > 0.f) ? acc : expm1f(acc);
            HP[b * 512 + k * 64 + hq + e] = v;
        }
    }
}

__global__ __launch_bounds__(256) void kB(const float* __restrict__ W_out,
                                          const float* __restrict__ bias,
                                          const float* __restrict__ ws,
                                          float* __restrict__ out) {
    const float* wsumT = ws;
    const float* HP    = ws + 4096;
    const int b = blockIdx.x;   // 0..31
    const int t = threadIdx.x;

    __shared__ float hp[512];
    __shared__ float s[16][64];
    __shared__ float who[64];
    __shared__ float red[256];

    hp[t]       = HP[b * 512 + t];
    hp[t + 256] = HP[b * 512 + 256 + t];
    __syncthreads();

    // who[c] = sum_j hp[j] * W_out[j,c] — 16-way j-parallel, float4 over c
    {
        const int cq = t & 15;    // c quad
        const int jg = t >> 4;    // 0..15
        float ax = 0.f, ay = 0.f, az = 0.f, aw = 0.f;
#pragma unroll 8
        for (int i = 0; i < 32; ++i) {
            const int j = jg + 16 * i;
            const float4 w = *reinterpret_cast<const float4*>(W_out + j * 64 + cq * 4);
            const float h = hp[j];
            ax += h * w.x; ay += h * w.y; az += h * w.z; aw += h * w.w;
        }
        s[jg][cq * 4 + 0] = ax; s[jg][cq * 4 + 1] = ay;
        s[jg][cq * 4 + 2] = az; s[jg][cq * 4 + 3] = aw;
    }
    __syncthreads();
    if (t < 64) {
        float sum = 0.f;
#pragma unroll
        for (int g = 0; g < 16; ++g) sum += s[g][t];
        who[t] = sum;
    }
    __syncthreads();

    // out[b,c] = bias[c] + sum_c2 who[c2] * WfSumT[c2][c]
    {
        const int c  = t & 63;
        const int cg = t >> 6;    // 0..3
        float acc = 0.f;
#pragma unroll
        for (int c2 = cg * 16; c2 < cg * 16 + 16; ++c2)
            acc += who[c2] * wsumT[c2 * 64 + c];
        red[t] = acc;
    }
    __syncthreads();
    if (t < 64)
        out[b * 64 + t] = red[t] + red[t + 64] + red[t + 128] + red[t + 192] + bias[t];
}

extern "C" void kernel_launch(void* const* d_in, const int* in_sizes, int n_in,
                              void* d_out, int out_size, void* d_ws, size_t ws_size,
                              hipStream_t stream) {
    const float* x       = (const float*)d_in[0]; // (32,12,128)
    const float* W_heads = (const float*)d_in[1]; // (8,128,64)
    // d_in[2], d_in[3]: a1_heads/a2_heads — unused (softmax of constant is uniform)
    const float* W_out   = (const float*)d_in[4]; // (512,64)
    // d_in[5], d_in[6]: a1_out/a2_out — unused
    const float* Wf      = (const float*)d_in[7]; // (64,32768)
    const float* bias    = (const float*)d_in[8]; // (64,)
    float* ws = (float*)d_ws;   // 16 KB wsumT + 64 KB HP

    kA<<<192, 256, 0, stream>>>(Wf, x, W_heads, ws);
    kB<<<32, 256, 0, stream>>>(W_out, bias, ws, (float*)d_out);
}